// Round 1
// baseline (308.009 us; speedup 1.0000x reference)
//
#include <hip/hip_runtime.h>
#include <math.h>

#define HW 65536
#define BN 16

// ws layout (floats):
//   ws[0] : mask-loss sum (global over B*HW)
//   ws[1] : skin-loss sum (global over B*HW)
//   per-b block of 121 at ws[2 + b*121]:
//     +0..2  : nocs  msum, cnt, dsum
//     +3..5  : locmap msum, cnt, dsum
//     +6..8  : rotmap msum, cnt, dsum
//     +9+j   : S[j]       (j<16)   = sum sig(score_j)*m
//     +25+c  : Nloc[c]    (c<48)   = sum sig(loc_c)*sig(score_{c/3})*m^2
//     +73+c  : Nrot[c]    (c<48)
// total = 2 + 4*121 = 486 floats

__device__ __forceinline__ float fsig(float x) {
    return __builtin_amdgcn_rcpf(1.0f + __expf(-x));
}

__device__ __forceinline__ float wred(float v) {
#pragma unroll
    for (int off = 32; off; off >>= 1) v += __shfl_xor(v, off, 64);
    return v;
}

__global__ __launch_bounds__(256) void mvpm_main(const float* __restrict__ outp,
                                                 const float* __restrict__ tarp,
                                                 float* __restrict__ ws) {
    const int b = blockIdx.y;
    const int p = blockIdx.x * 256 + threadIdx.x;
    const float* ob = outp + (size_t)b * 134 * HW;
    const float* tb = tarp + (size_t)b * 101 * HW;
    const int lane = threadIdx.x & 63;
    const int wv = threadIdx.x >> 6;

    __shared__ float red[123][4];

#define STAGE(slot, val)                          \
    do {                                          \
        float _r = wred(val);                     \
        if (lane == 0) red[(slot)][wv] = _r;      \
    } while (0)

    const float m  = tb[3 * HW + p];
    const float mm = m * m;
    const bool sel = m > 0.7f;

    // ---- joint loop: scores + loc/rot maps ----
    float dsq_loc = 0.0f, dsq_rot = 0.0f;
    for (int j = 0; j < BN; ++j) {
        float w = fsig(ob[(118 + j) * HW + p]) * m;   // sig(score)*m
        STAGE(11 + j, w);
#pragma unroll
        for (int k = 0; k < 3; ++k) {
            const int c = 3 * j + k;
            float so = fsig(ob[(4 + c) * HW + p]);
            float st = fsig(tb[(4 + c) * HW + p]);
            float d  = so - st;
            dsq_loc += d * d;
            STAGE(27 + c, so * w * m);                // sig(map)*sig(score)*m^2

            float so2 = fsig(ob[(52 + c) * HW + p]);
            float st2 = fsig(tb[(52 + c) * HW + p]);
            float d2  = so2 - st2;
            dsq_rot += d2 * d2;
            STAGE(75 + c, so2 * w * m);
        }
    }

    // ---- nocs masked-L2 ----
    float d0 = ob[0 * HW + p] - tb[0 * HW + p];
    float d1 = ob[1 * HW + p] - tb[1 * HW + p];
    float d2n = ob[2 * HW + p] - tb[2 * HW + p];
    float dn = sqrtf(d0 * d0 + d1 * d1 + d2n * d2n);
    STAGE(2, sel ? dn : 0.0f);
    STAGE(3, (sel && dn != 0.0f) ? 1.0f : 0.0f);
    STAGE(4, dn);

    float dnl = sqrtf(dsq_loc);
    STAGE(5, sel ? dnl : 0.0f);
    STAGE(6, (sel && dnl != 0.0f) ? 1.0f : 0.0f);
    STAGE(7, dnl);

    float dnr = sqrtf(dsq_rot);
    STAGE(8, sel ? dnr : 0.0f);
    STAGE(9, (sel && dnr != 0.0f) ? 1.0f : 0.0f);
    STAGE(10, dnr);

    // ---- mask BCE:  m*logsig(x) + (1-m)*logsig(-x) ----
    {
        float ml = ob[3 * HW + p];
        float t  = __logf(1.0f + __expf(-fabsf(ml)));
        float v  = m * fminf(ml, 0.0f) + (1.0f - m) * fminf(-ml, 0.0f) - t;
        STAGE(0, v);
    }

    // ---- skin cross-entropy over 18 channels ----
    {
        float x[18];
#pragma unroll
        for (int k = 0; k < 18; ++k) x[k] = ob[(100 + k) * HW + p];
        float mx = x[0];
#pragma unroll
        for (int k = 1; k < 18; ++k) mx = fmaxf(mx, x[k]);
        float se = 0.0f;
#pragma unroll
        for (int k = 0; k < 18; ++k) se += __expf(x[k] - mx);
        float lse = mx + __logf(se);
        int lab = (int)tb[100 * HW + p];
        lab = lab < 0 ? 0 : (lab > 17 ? 17 : lab);
        float xl = x[0];
#pragma unroll
        for (int k = 1; k < 18; ++k) xl = (lab == k) ? x[k] : xl;
        STAGE(1, lse - xl);
    }

    __syncthreads();
    if (threadIdx.x < 123) {
        float s = red[threadIdx.x][0] + red[threadIdx.x][1] +
                  red[threadIdx.x][2] + red[threadIdx.x][3];
        int g = (threadIdx.x < 2) ? threadIdx.x : (2 + b * 121 + (threadIdx.x - 2));
        atomicAdd(&ws[g], s);
    }
#undef STAGE
}

__global__ __launch_bounds__(64) void mvpm_fin(const float* __restrict__ ws,
                                               const float* __restrict__ tp,
                                               float* __restrict__ o) {
    const int t = threadIdx.x;      // 64 threads = (b, j)
    const int b = t >> 4;
    const int j = t & 15;
    const int base = 2 + b * 121;

    float S = ws[base + 9 + j] + 1e-5f;
    float ln = 0.0f, rn = 0.0f;
#pragma unroll
    for (int c = 0; c < 3; ++c) {
        float pl = ws[base + 25 + 3 * j + c] / S;
        float tl = 1.0f / (1.0f + expf(-tp[t * 6 + c]));
        ln += (pl - tl) * (pl - tl);
        float pr = ws[base + 73 + 3 * j + c] / S;
        float tr = 1.0f / (1.0f + expf(-tp[t * 6 + 3 + c]));
        rn += (pr - tr) * (pr - tr);
    }
    ln = sqrtf(ln);
    rn = sqrtf(rn);
    float lsum = wred(ln);
    float rsum = wred(rn);

    if (t == 0) {
        float nocs = 0.0f, locm = 0.0f, rotm = 0.0f;
        for (int bb = 0; bb < 4; ++bb) {
            int ba = 2 + bb * 121;
            nocs += (ws[ba + 1] > 0.5f) ? ws[ba + 0] / ws[ba + 1] : ws[ba + 2] * (1.0f / HW);
            locm += (ws[ba + 4] > 0.5f) ? ws[ba + 3] / ws[ba + 4] : ws[ba + 5] * (1.0f / HW);
            rotm += (ws[ba + 7] > 0.5f) ? ws[ba + 6] / ws[ba + 7] : ws[ba + 8] * (1.0f / HW);
        }
        o[0] = nocs * 0.25f;                  // nocs_loss
        o[1] = -ws[0] / (4.0f * HW);          // mask_loss
        o[2] = lsum * (1.0f / 64.0f);         // loc_loss
        o[3] = locm * 0.25f;                  // loc_map_loss
        o[4] = rsum * (1.0f / 64.0f);         // rot_loss
        o[5] = rotm * 0.25f;                  // rot_map_loss
        o[6] = ws[1] / (4.0f * HW);           // skin_loss
    }
}

extern "C" void kernel_launch(void* const* d_in, const int* in_sizes, int n_in,
                              void* d_out, int out_size, void* d_ws, size_t ws_size,
                              hipStream_t stream) {
    const float* outp = (const float*)d_in[0];   // (4,134,256,256)
    const float* tarp = (const float*)d_in[1];   // (4,101,256,256)
    const float* tpos = (const float*)d_in[2];   // (4,16,6)
    float* o  = (float*)d_out;                   // 7 floats
    float* ws = (float*)d_ws;

    hipMemsetAsync(d_ws, 0, 486 * sizeof(float), stream);
    dim3 grid(HW / 256, 4);
    mvpm_main<<<grid, 256, 0, stream>>>(outp, tarp, ws);
    mvpm_fin<<<1, 64, 0, stream>>>(ws, tpos, o);
}

// Round 2
// 294.267 us; speedup vs baseline: 1.0467x; 1.0467x over previous
//
#include <hip/hip_runtime.h>
#include <math.h>

#define HW 65536
#define BN 16

// ws layout (floats):
//   ws[0] : mask-loss sum (global over B*HW)
//   ws[1] : skin-loss sum (global over B*HW)
//   per-b block of 9 at ws[2 + b*9]:
//     +0..2 : nocs   msum, cnt, dsum
//     +3..5 : locmap msum, cnt, dsum
//     +6..8 : rotmap msum, cnt, dsum
//   per-(b,j) block of 7 at ws[38 + (b*16+j)*7]:
//     +0    : S      = sum sig(score_j)*m
//     +1..3 : Nloc_c = sum sig(loc_c)*sig(score_j)*m^2
//     +4..6 : Nrot_c
// total = 38 + 64*7 = 486 floats

__device__ __forceinline__ float fsig(float x) {
    return __builtin_amdgcn_rcpf(1.0f + __expf(-x));
}

__device__ __forceinline__ float wred(float v) {
#pragma unroll
    for (int off = 32; off; off >>= 1) v += __shfl_xor(v, off, 64);
    return v;
}

// ---------------- Kernel A: pixel-parallel losses (11 accumulators) -------
__global__ __launch_bounds__(256) void mvpm_pix(const float* __restrict__ outp,
                                                const float* __restrict__ tarp,
                                                float* __restrict__ ws) {
    const int b = blockIdx.y;
    const int p = blockIdx.x * 256 + threadIdx.x;
    const float* ob = outp + (size_t)b * 134 * HW;
    const float* tb = tarp + (size_t)b * 101 * HW;
    const int lane = threadIdx.x & 63;
    const int wv = threadIdx.x >> 6;

    const float m = tb[3 * HW + p];
    const bool sel = m > 0.7f;

    // ---- mask BCE: m*logsig(x) + (1-m)*logsig(-x) ----
    const float ml = ob[3 * HW + p];
    const float bce = m * fminf(ml, 0.0f) + (1.0f - m) * fminf(-ml, 0.0f)
                      - __logf(1.0f + __expf(-fabsf(ml)));

    // ---- nocs masked-L2 ----
    float d0 = ob[0 * HW + p] - tb[0 * HW + p];
    float d1 = ob[1 * HW + p] - tb[1 * HW + p];
    float d2 = ob[2 * HW + p] - tb[2 * HW + p];
    const float dn = sqrtf(d0 * d0 + d1 * d1 + d2 * d2);

    // ---- loc/rot map masked-L2 (48-channel norms) ----
    float dsl = 0.0f, dsr = 0.0f;
#pragma unroll 4
    for (int c = 0; c < 48; ++c) {
        float so = fsig(ob[(4 + c) * HW + p]);
        float st = fsig(tb[(4 + c) * HW + p]);
        float d = so - st;
        dsl += d * d;
        float so2 = fsig(ob[(52 + c) * HW + p]);
        float st2 = fsig(tb[(52 + c) * HW + p]);
        float dd = so2 - st2;
        dsr += dd * dd;
    }
    const float dnl = sqrtf(dsl);
    const float dnr = sqrtf(dsr);

    // ---- skin cross-entropy over 18 channels ----
    float x[18];
#pragma unroll
    for (int k = 0; k < 18; ++k) x[k] = ob[(100 + k) * HW + p];
    float mx = x[0];
#pragma unroll
    for (int k = 1; k < 18; ++k) mx = fmaxf(mx, x[k]);
    float se = 0.0f;
#pragma unroll
    for (int k = 0; k < 18; ++k) se += __expf(x[k] - mx);
    float lse = mx + __logf(se);
    int lab = (int)tb[100 * HW + p];
    lab = lab < 0 ? 0 : (lab > 17 ? 17 : lab);
    float xl = x[0];
#pragma unroll
    for (int k = 1; k < 18; ++k) xl = (lab == k) ? x[k] : xl;
    const float skin = lse - xl;

    // ---- 11 wave reductions (independent trees — ILP-friendly) ----
    float v[11];
    v[0] = bce;
    v[1] = skin;
    v[2] = sel ? dn : 0.0f;
    v[3] = (sel && dn != 0.0f) ? 1.0f : 0.0f;
    v[4] = dn;
    v[5] = sel ? dnl : 0.0f;
    v[6] = (sel && dnl != 0.0f) ? 1.0f : 0.0f;
    v[7] = dnl;
    v[8] = sel ? dnr : 0.0f;
    v[9] = (sel && dnr != 0.0f) ? 1.0f : 0.0f;
    v[10] = dnr;

#pragma unroll
    for (int off = 32; off; off >>= 1) {
#pragma unroll
        for (int i = 0; i < 11; ++i) v[i] += __shfl_xor(v[i], off, 64);
    }

    __shared__ float red[11][4];
    if (lane == 0) {
#pragma unroll
        for (int i = 0; i < 11; ++i) red[i][wv] = v[i];
    }
    __syncthreads();
    if (threadIdx.x < 11) {
        float s = red[threadIdx.x][0] + red[threadIdx.x][1] +
                  red[threadIdx.x][2] + red[threadIdx.x][3];
        int g = (threadIdx.x < 2) ? threadIdx.x : (2 + b * 9 + (threadIdx.x - 2));
        atomicAdd(&ws[g], s);
    }
}

// ---------------- Kernel B: per-joint weighted sums (7 accumulators) ------
__global__ __launch_bounds__(256) void mvpm_joint(const float* __restrict__ outp,
                                                  const float* __restrict__ tarp,
                                                  float* __restrict__ ws) {
    const int bj = blockIdx.y;            // b*16 + j
    const int b = bj >> 4;
    const int j = bj & 15;
    const float* ob = outp + (size_t)b * 134 * HW;
    const float* mp = tarp + (size_t)b * 101 * HW + 3 * HW;
    const float* sp = ob + (118 + j) * HW;
    const float* lp = ob + (4 + 3 * j) * HW;
    const float* rp = ob + (52 + 3 * j) * HW;

    const int base = blockIdx.x * 4096 + threadIdx.x;   // 16 chunks of 4096
    const int lane = threadIdx.x & 63;
    const int wv = threadIdx.x >> 6;

    float S = 0.0f, nl0 = 0.0f, nl1 = 0.0f, nl2 = 0.0f,
          nr0 = 0.0f, nr1 = 0.0f, nr2 = 0.0f;
#pragma unroll 4
    for (int i = 0; i < 16; ++i) {
        const int p = base + i * 256;
        const float m = mp[p];
        const float w = fsig(sp[p]) * m;
        S += w;
        const float wm = w * m;
        nl0 += fsig(lp[p]) * wm;
        nl1 += fsig(lp[HW + p]) * wm;
        nl2 += fsig(lp[2 * HW + p]) * wm;
        nr0 += fsig(rp[p]) * wm;
        nr1 += fsig(rp[HW + p]) * wm;
        nr2 += fsig(rp[2 * HW + p]) * wm;
    }

    float v[7] = {S, nl0, nl1, nl2, nr0, nr1, nr2};
#pragma unroll
    for (int off = 32; off; off >>= 1) {
#pragma unroll
        for (int i = 0; i < 7; ++i) v[i] += __shfl_xor(v[i], off, 64);
    }

    __shared__ float red[7][4];
    if (lane == 0) {
#pragma unroll
        for (int i = 0; i < 7; ++i) red[i][wv] = v[i];
    }
    __syncthreads();
    if (threadIdx.x < 7) {
        float s = red[threadIdx.x][0] + red[threadIdx.x][1] +
                  red[threadIdx.x][2] + red[threadIdx.x][3];
        atomicAdd(&ws[38 + bj * 7 + threadIdx.x], s);
    }
}

// ---------------- finalize -----------------------------------------------
__global__ __launch_bounds__(64) void mvpm_fin(const float* __restrict__ ws,
                                               const float* __restrict__ tp,
                                               float* __restrict__ o) {
    const int t = threadIdx.x;      // 64 threads = (b, j)
    const int base = 38 + t * 7;

    float S = ws[base] + 1e-5f;
    float ln = 0.0f, rn = 0.0f;
#pragma unroll
    for (int c = 0; c < 3; ++c) {
        float pl = ws[base + 1 + c] / S;
        float tl = 1.0f / (1.0f + expf(-tp[t * 6 + c]));
        ln += (pl - tl) * (pl - tl);
        float pr = ws[base + 4 + c] / S;
        float tr = 1.0f / (1.0f + expf(-tp[t * 6 + 3 + c]));
        rn += (pr - tr) * (pr - tr);
    }
    ln = sqrtf(ln);
    rn = sqrtf(rn);
    float lsum = wred(ln);
    float rsum = wred(rn);

    if (t == 0) {
        float nocs = 0.0f, locm = 0.0f, rotm = 0.0f;
        for (int bb = 0; bb < 4; ++bb) {
            int ba = 2 + bb * 9;
            nocs += (ws[ba + 1] > 0.5f) ? ws[ba + 0] / ws[ba + 1] : ws[ba + 2] * (1.0f / HW);
            locm += (ws[ba + 4] > 0.5f) ? ws[ba + 3] / ws[ba + 4] : ws[ba + 5] * (1.0f / HW);
            rotm += (ws[ba + 7] > 0.5f) ? ws[ba + 6] / ws[ba + 7] : ws[ba + 8] * (1.0f / HW);
        }
        o[0] = nocs * 0.25f;                  // nocs_loss
        o[1] = -ws[0] / (4.0f * HW);          // mask_loss
        o[2] = lsum * (1.0f / 64.0f);         // loc_loss
        o[3] = locm * 0.25f;                  // loc_map_loss
        o[4] = rsum * (1.0f / 64.0f);         // rot_loss
        o[5] = rotm * 0.25f;                  // rot_map_loss
        o[6] = ws[1] / (4.0f * HW);           // skin_loss
    }
}

extern "C" void kernel_launch(void* const* d_in, const int* in_sizes, int n_in,
                              void* d_out, int out_size, void* d_ws, size_t ws_size,
                              hipStream_t stream) {
    const float* outp = (const float*)d_in[0];   // (4,134,256,256)
    const float* tarp = (const float*)d_in[1];   // (4,101,256,256)
    const float* tpos = (const float*)d_in[2];   // (4,16,6)
    float* o  = (float*)d_out;                   // 7 floats
    float* ws = (float*)d_ws;

    hipMemsetAsync(d_ws, 0, 486 * sizeof(float), stream);
    dim3 gA(HW / 256, 4);                        // 1024 blocks, 1 px/thread
    mvpm_pix<<<gA, 256, 0, stream>>>(outp, tarp, ws);
    dim3 gB(16, 64);                             // 16 chunks x (b,j)
    mvpm_joint<<<gB, 256, 0, stream>>>(outp, tarp, ws);
    mvpm_fin<<<1, 64, 0, stream>>>(ws, tpos, o);
}